// Round 13
// baseline (512.911 us; speedup 1.0000x reference)
//
#include <hip/hip_runtime.h>

typedef __attribute__((ext_vector_type(8))) short short8;
typedef __attribute__((ext_vector_type(4))) float f32x4;

static constexpr int NN = 100000;
static constexpr int NE = 1600000;
static constexpr int DD = 128;
static constexpr int NBUCK = 784;     // 128 nodes per bucket (dst >> 7); 782 used
static constexpr int CAP = 2560;      // mean 2048 + ~11 sigma

// ws layout in 4-byte words (peak 58.6 MB)
static constexpr int OFF_GCUR  = 0;        // 1024
static constexpr int OFF_BBASE = 1024;     // 1024 (need NBUCK+1)
static constexpr int OFF_OFFS  = 2048;     // NN+1
static constexpr int OFF_INV   = 102052;   // NN
static constexpr int OFF_WT    = 202056;   // 3*8*128*32 bf16 = 49152 words (16B aligned)
static constexpr int OFF_SS    = 251208;   // NE
static constexpr int OFF_HB    = 1851216;  // NN*64 (h, bf16, in-place across layers)
static constexpr int OFF_HNB   = 8251216;  // NN*64 (h_neigh bf16; ebuf aliases)

__device__ inline ushort f2b(float f) {
  uint u = __builtin_bit_cast(uint, f);
  uint r = (u + 0x7fffu + ((u >> 16) & 1u)) >> 16;
  return (ushort)r;
}
__device__ inline float b2f(ushort b) {
  uint u = ((uint)b) << 16;
  return __builtin_bit_cast(float, u);
}

// Fused pre-pass: [0,12500) x->bf16, [12500,12884) weight repack, [12884,12888) zero gcur
__global__ __launch_bounds__(256) void k_pre(const float* __restrict__ x,
                                             const float* __restrict__ Ws,
                                             const float* __restrict__ Wn,
                                             ushort* __restrict__ hb,
                                             ushort* __restrict__ WtP,
                                             int* __restrict__ gcur) {
  int b = blockIdx.x, t = threadIdx.x;
  if (b < 12500) {
    int i = b * 256 + t;               // < 3,200,000 = NN*32
    float4 v = *(const float4*)(x + (size_t)i * 4);
    uint2 p;
    p.x = (uint)f2b(v.x) | ((uint)f2b(v.y) << 16);
    p.y = (uint)f2b(v.z) | ((uint)f2b(v.w) << 16);
    *(uint2*)(hb + (size_t)i * 4) = p;
  } else if (b < 12884) {
    // WtP[((l*8+kt)*128+col)*32 + kg*8 + j] = W[l][kt*32+kg*8+j][col]
    int i = (b - 12500) * 256 + t;     // < 98304 = 3*8*128*32
    int j = i & 7;
    int kg = (i >> 3) & 3;
    int col = (i >> 5) & 127;
    int kt = (i >> 12) & 7;
    int l = i >> 15;
    int k = kt * 32 + kg * 8 + j;
    float v = (k < 128) ? Ws[((size_t)l * 128 + k) * 128 + col]
                        : Wn[((size_t)l * 128 + (k - 128)) * 128 + col];
    WtP[i] = f2b(v);
  } else {
    int i = (b - 12884) * 256 + t;
    if (i < NBUCK) gcur[i] = 0;
  }
}

// Pass 1: bucket edges by dst>>7; packed entry = (dst&127)<<17 | src
__global__ __launch_bounds__(512) void k_bucket(const int* __restrict__ src,
                                                const int* __restrict__ dst,
                                                int* __restrict__ gcur,
                                                int* __restrict__ ebuf) {
  __shared__ int cnt[2][NBUCK];
  __shared__ int base[NBUCK];
  int t = threadIdx.x;
  int b0 = blockIdx.x * 4096;
  int half = t & 1;
  for (int i = t; i < NBUCK; i += 512) { cnt[0][i] = 0; cnt[1][i] = 0; }
  __syncthreads();
  int dv[8], pv[8];
#pragma unroll
  for (int j = 0; j < 8; ++j) {
    int idx = b0 + j * 512 + t;
    if (idx < NE) {
      int d = dst[idx];
      dv[j] = d;
      pv[j] = atomicAdd(&cnt[half][d >> 7], 1);
    } else dv[j] = -1;
  }
  __syncthreads();
  for (int i = t; i < NBUCK; i += 512)
    base[i] = atomicAdd(&gcur[i], cnt[0][i] + cnt[1][i]);
  __syncthreads();
#pragma unroll
  for (int j = 0; j < 8; ++j) {
    if (dv[j] >= 0) {
      int idx = b0 + j * 512 + t;
      int b = dv[j] >> 7;
      int pos = pv[j] + (half ? cnt[0][b] : 0);
      ebuf[(size_t)b * CAP + base[b] + pos] = ((dv[j] & 127) << 17) | src[idx];
    }
  }
}

// exclusive scan over NBUCK bucket counts -> bbase[0..NBUCK]
__global__ __launch_bounds__(512) void k_bscan(const int* __restrict__ gcur,
                                               int* __restrict__ bbase) {
  __shared__ int sc[1024];
  int t = threadIdx.x;
  int v0 = (t < NBUCK) ? gcur[t] : 0;
  int v1 = (t + 512 < NBUCK) ? gcur[t + 512] : 0;
  sc[t] = v0; sc[t + 512] = v1;
  __syncthreads();
  for (int off = 1; off < 1024; off <<= 1) {
    int a0 = (t >= off) ? sc[t - off] : 0;
    int a1 = (t + 512 >= off) ? sc[t + 512 - off] : 0;
    __syncthreads();
    sc[t] += a0; sc[t + 512] += a1;
    __syncthreads();
  }
  if (t < NBUCK) bbase[t] = sc[t] - v0;
  if (t + 512 < NBUCK) bbase[t + 512] = sc[t + 512] - v1;
  if (t == 0) bbase[NBUCK] = NE;
}

// Pass 2: per-bucket (128 nodes) hist -> offs/inv -> LDS counting sort -> streamed ss
__global__ __launch_bounds__(256) void k_sort(const int* __restrict__ ebuf,
                                              const int* __restrict__ bbase,
                                              int* __restrict__ offs,
                                              float* __restrict__ inv,
                                              int* __restrict__ ss) {
  __shared__ int cnt[128];
  __shared__ int sbase[128];
  __shared__ int scan[128];
  __shared__ int sarr[CAP];
  int b = blockIdx.x, t = threadIdx.x;
  int base0 = bbase[b];
  int n = bbase[b + 1] - base0;
  if (t < 128) cnt[t] = 0;
  __syncthreads();
  const int* eb = ebuf + (size_t)b * CAP;
  for (int i = t; i < n; i += 256) atomicAdd(&cnt[(eb[i] >> 17) & 127], 1);
  __syncthreads();
  int s = 0;
  if (t < 128) { s = cnt[t]; scan[t] = s; }
  __syncthreads();
  for (int off = 1; off < 128; off <<= 1) {
    int u = (t < 128 && t >= off) ? scan[t - off] : 0;
    __syncthreads();
    if (t < 128) scan[t] += u;
    __syncthreads();
  }
  if (t < 128) {
    int eb2 = scan[t] - s;
    sbase[t] = eb2;
    int g = b * 128 + t;
    if (g < NN) {
      offs[g] = base0 + eb2;
      inv[g] = 1.0f / (float)(s > 1 ? s : 1);
    }
    cnt[t] = 0;       // reuse as cursor
  }
  if (b == NBUCK - 1 && t == 0) offs[NN] = NE;
  __syncthreads();
  for (int i = t; i < n; i += 256) {
    int e = eb[i];
    int ln = (e >> 17) & 127;
    int p = sbase[ln] + atomicAdd(&cnt[ln], 1);
    sarr[p] = e & 131071;
  }
  __syncthreads();
  for (int i = t; i < n; i += 256) ss[base0 + i] = sarr[i];
}

// 4 nodes per wave (16 lanes/row, uint4 = 8 bf16/lane), unroll 8, fp32 accumulate
__global__ __launch_bounds__(256) void k_agg3(const ushort* __restrict__ h,
                                              const int* __restrict__ offs,
                                              const int* __restrict__ ss,
                                              const float* __restrict__ inv_deg,
                                              ushort* __restrict__ hN) {
  int gid = blockIdx.x * blockDim.x + threadIdx.x;
  int wid = gid >> 6;
  int lane = threadIdx.x & 63;
  int q = lane >> 4, l16 = lane & 15;
  int v = wid * 4 + q;
  int beg = offs[v], end = offs[v + 1];
  float a0 = 0, a1 = 0, a2 = 0, a3 = 0, a4 = 0, a5 = 0, a6 = 0, a7 = 0;
  const ushort* hp = h + (size_t)l16 * 8;
#define ACC8(u) { a0 += b2f((ushort)u.x); a1 += b2f((ushort)(u.x >> 16)); \
                  a2 += b2f((ushort)u.y); a3 += b2f((ushort)(u.y >> 16)); \
                  a4 += b2f((ushort)u.z); a5 += b2f((ushort)(u.z >> 16)); \
                  a6 += b2f((ushort)u.w); a7 += b2f((ushort)(u.w >> 16)); }
  int e = beg;
  for (; e + 7 < end; e += 8) {
    uint4 u0 = *(const uint4*)(hp + (size_t)ss[e + 0] * DD);
    uint4 u1 = *(const uint4*)(hp + (size_t)ss[e + 1] * DD);
    uint4 u2 = *(const uint4*)(hp + (size_t)ss[e + 2] * DD);
    uint4 u3 = *(const uint4*)(hp + (size_t)ss[e + 3] * DD);
    uint4 u4 = *(const uint4*)(hp + (size_t)ss[e + 4] * DD);
    uint4 u5 = *(const uint4*)(hp + (size_t)ss[e + 5] * DD);
    uint4 u6 = *(const uint4*)(hp + (size_t)ss[e + 6] * DD);
    uint4 u7 = *(const uint4*)(hp + (size_t)ss[e + 7] * DD);
    ACC8(u0) ACC8(u1) ACC8(u2) ACC8(u3) ACC8(u4) ACC8(u5) ACC8(u6) ACC8(u7)
  }
  for (; e < end; ++e) {
    uint4 u0 = *(const uint4*)(hp + (size_t)ss[e] * DD);
    ACC8(u0)
  }
#undef ACC8
  float w = inv_deg[v];
  a0 *= w; a1 *= w; a2 *= w; a3 *= w; a4 *= w; a5 *= w; a6 *= w; a7 *= w;
  uint4 p;
  p.x = (uint)f2b(a0) | ((uint)f2b(a1) << 16);
  p.y = (uint)f2b(a2) | ((uint)f2b(a3) << 16);
  p.z = (uint)f2b(a4) | ((uint)f2b(a5) << 16);
  p.w = (uint)f2b(a6) | ((uint)f2b(a7) << 16);
  *(uint4*)(hN + (size_t)v * DD + l16 * 8) = p;
}

// h_out = relu([hA|hN] @ W + bias). 32 rows/block (3125 blocks), 4 waves =
// 4 col-quarters; B-fragments in registers; in-place safe via one barrier.
__global__ __launch_bounds__(256) void k_gemm3(
    const ushort* __restrict__ hA, const ushort* __restrict__ hNb,
    const ushort* __restrict__ WtP, const float* __restrict__ bias,
    ushort* __restrict__ hOutB, float* __restrict__ outF, int writeF) {
  int w = threadIdx.x >> 6;
  int lane = threadIdx.x & 63;
  int r = lane & 15, kg = lane >> 4;
  int colbase = w * 32;
  int row0 = blockIdx.x * 32;

  short8 bfrag[8][2];
#pragma unroll
  for (int kt = 0; kt < 8; ++kt)
#pragma unroll
    for (int nt = 0; nt < 2; ++nt) {
      int col = colbase + nt * 16 + r;
      bfrag[kt][nt] = *(const short8*)(WtP + ((size_t)(kt * 128 + col) * 4 + kg) * 8);
    }
  float bv[2];
  bv[0] = bias[colbase + r];
  bv[1] = bias[colbase + 16 + r];

  int ra0 = row0 + r;
  int ra1 = row0 + 16 + r;

  f32x4 acc[2][2];
#pragma unroll
  for (int mt = 0; mt < 2; ++mt)
#pragma unroll
    for (int nt = 0; nt < 2; ++nt) acc[mt][nt] = (f32x4)0.f;

#pragma unroll
  for (int kt = 0; kt < 8; ++kt) {
    const ushort* hs = (kt < 4) ? hA : hNb;
    int kk = (kt & 3) * 32 + kg * 8;
    short8 a0 = *(const short8*)(hs + (size_t)ra0 * DD + kk);
    short8 a1 = *(const short8*)(hs + (size_t)ra1 * DD + kk);
    acc[0][0] = __builtin_amdgcn_mfma_f32_16x16x32_bf16(a0, bfrag[kt][0], acc[0][0], 0, 0, 0);
    acc[0][1] = __builtin_amdgcn_mfma_f32_16x16x32_bf16(a0, bfrag[kt][1], acc[0][1], 0, 0, 0);
    acc[1][0] = __builtin_amdgcn_mfma_f32_16x16x32_bf16(a1, bfrag[kt][0], acc[1][0], 0, 0, 0);
    acc[1][1] = __builtin_amdgcn_mfma_f32_16x16x32_bf16(a1, bfrag[kt][1], acc[1][1], 0, 0, 0);
  }

  __syncthreads();   // all reads of this block's 32 rows complete before any write

#pragma unroll
  for (int mt = 0; mt < 2; ++mt) {
#pragma unroll
    for (int j = 0; j < 4; ++j) {
      int row = row0 + mt * 16 + kg * 4 + j;
#pragma unroll
      for (int nt = 0; nt < 2; ++nt) {
        float val = fmaxf(acc[mt][nt][j] + bv[nt], 0.f);
        int col = colbase + nt * 16 + r;
        if (writeF) outF[(size_t)row * DD + col] = val;
        else        hOutB[(size_t)row * DD + col] = f2b(val);
      }
    }
  }
}

extern "C" void kernel_launch(void* const* d_in, const int* in_sizes, int n_in,
                              void* d_out, int out_size, void* d_ws, size_t ws_size,
                              hipStream_t stream) {
  const float* x    = (const float*)d_in[0];
  const float* Ws   = (const float*)d_in[1];
  const float* Wn   = (const float*)d_in[2];
  const float* bias = (const float*)d_in[3];
  const int*   src  = (const int*)d_in[4];
  const int*   dst  = (const int*)d_in[5];
  float* out = (float*)d_out;

  int* ws      = (int*)d_ws;
  int* gcur    = ws + OFF_GCUR;
  int* bbase   = ws + OFF_BBASE;
  int* offs    = ws + OFF_OFFS;
  float* inv   = (float*)(ws + OFF_INV);
  ushort* WtP  = (ushort*)(ws + OFF_WT);
  int* ssorted = ws + OFF_SS;
  ushort* hB   = (ushort*)(ws + OFF_HB);
  ushort* hNb  = (ushort*)(ws + OFF_HNB);
  int* ebuf    = ws + OFF_HNB;            // dead after k_sort; hNb reuses

  k_pre<<<12888, 256, 0, stream>>>(x, Ws, Wn, hB, WtP, gcur);
  k_bucket<<<(NE + 4095) / 4096, 512, 0, stream>>>(src, dst, gcur, ebuf);
  k_bscan<<<1, 512, 0, stream>>>(gcur, bbase);
  k_sort<<<NBUCK, 256, 0, stream>>>(ebuf, bbase, offs, inv, ssorted);

  // 3 SAGE layers; h stays in hB (in-place GEMM), last layer writes f32 out
  for (int l = 0; l < 3; ++l) {
    k_agg3<<<NN / 16, 256, 0, stream>>>(hB, offs, ssorted, inv, hNb);
    k_gemm3<<<NN / 32, 256, 0, stream>>>(
        hB, hNb, WtP + (size_t)l * 8 * 128 * 32, bias + l * DD, hB, out, l == 2 ? 1 : 0);
  }
}